// Round 3
// baseline (2071.170 us; speedup 1.0000x reference)
//
#include <hip/hip_runtime.h>
#include <stdint.h>

typedef _Float16 half_t;
typedef _Float16 half8 __attribute__((ext_vector_type(8)));
typedef float floatx4 __attribute__((ext_vector_type(4)));

#define B_ 8
#define C_ 512
#define H_ 4096
#define HB 256
#define NB 15
#define CUT_ 8
#define M_ 2048
#define INV_TEMP (1.0f/0.7f)
#define NEG (-1e9f)

// K tiles pre-padded to LDS layout: [32 keys][528 halves] (33 KB = 33 x 1KB DMA chunks)
// V tiles: [512 c][32 keys] contiguous (32 KB) -- consumed by per-wave b128 reg loads.
#define KROW 528
#define KT_BYTES 33792u
#define VT_BYTES 32768u

// Workspace layout (bytes)
#define SQ_OFFB   0u            // B*3840 floats
#define SK_OFFB   122880u
#define ST_OFFB   245760u       // B*2 floats
#define PERM_OFFB 245824u       // B*225 floats
#define KC16_OFFB 262144u       // [B][64][32][528] fp16 = 17.3 MB
#define VC16_OFFB (262144u + 17301504u)   // [B][64][512][32] fp16 = 16.8 MB
#define WS_NEED   (262144u + 17301504u + 16777216u)

// ---------------- threefry2x32 (JAX partitionable, key=(0,42)) ---------------
__device__ __forceinline__ unsigned rotl32(unsigned x, unsigned n) {
    return (x << n) | (x >> (32u - n));
}
__device__ __forceinline__ void threefry2x32(unsigned k0, unsigned k1,
                                             unsigned x0, unsigned x1,
                                             unsigned &o0, unsigned &o1) {
    unsigned k2 = 0x1BD11BDAu ^ k0 ^ k1;
    x0 += k0; x1 += k1;
    x0+=x1; x1=rotl32(x1,13); x1^=x0;
    x0+=x1; x1=rotl32(x1,15); x1^=x0;
    x0+=x1; x1=rotl32(x1,26); x1^=x0;
    x0+=x1; x1=rotl32(x1, 6); x1^=x0;
    x0+=k1; x1+=k2+1u;
    x0+=x1; x1=rotl32(x1,17); x1^=x0;
    x0+=x1; x1=rotl32(x1,29); x1^=x0;
    x0+=x1; x1=rotl32(x1,16); x1^=x0;
    x0+=x1; x1=rotl32(x1,24); x1^=x0;
    x0+=k2; x1+=k0+2u;
    x0+=x1; x1=rotl32(x1,13); x1^=x0;
    x0+=x1; x1=rotl32(x1,15); x1^=x0;
    x0+=x1; x1=rotl32(x1,26); x1^=x0;
    x0+=x1; x1=rotl32(x1, 6); x1^=x0;
    x0+=k0; x1+=k1+3u;
    x0+=x1; x1=rotl32(x1,17); x1^=x0;
    x0+=x1; x1=rotl32(x1,29); x1^=x0;
    x0+=x1; x1=rotl32(x1,16); x1^=x0;
    x0+=x1; x1=rotl32(x1,24); x1^=x0;
    x0+=k1; x1+=k2+4u;
    x0+=x1; x1=rotl32(x1,13); x1^=x0;
    x0+=x1; x1=rotl32(x1,15); x1^=x0;
    x0+=x1; x1=rotl32(x1,26); x1^=x0;
    x0+=x1; x1=rotl32(x1, 6); x1^=x0;
    x0+=k2; x1+=k0+5u;
    o0 = x0; o1 = x1;
}

// -------- async global->LDS DMA, 8-wave block (uniform LDS base + lane*16) ---
__device__ __forceinline__ void stage_tile8(const char* gsrc, char* lbase,
                                            int w, int lane, int nchunk) {
    #pragma unroll
    for (int i = 0; i < 5; i++) {
        int cc = w + 8*i;                 // wave-uniform chunk id
        if (cc < nchunk) {
            __builtin_amdgcn_global_load_lds(
                (const __attribute__((address_space(1))) void*)(uintptr_t)
                    (gsrc + (size_t)cc*1024u + (size_t)lane*16u),
                (__attribute__((address_space(3))) void*)(uintptr_t)
                    (lbase + (size_t)cc*1024u),
                16, 0, 0);
        }
    }
}

// ---------------- Kernel 1: per-(b,h) channel means of q,k -------------------
__global__ void colmean_kernel(const float* __restrict__ q, const float* __restrict__ k,
                               float* __restrict__ sq, float* __restrict__ sk) {
    int id  = blockIdx.x * 256 + threadIdx.x;
    int h   = id % 3840;
    int rest= id / 3840;
    int b   = rest % 8;
    int seg = rest / 8;
    int c0  = seg * 64;
    const float* qb = q + ((size_t)b*C_ + c0) * H_ + h;
    const float* kb = k + ((size_t)b*C_ + c0) * H_ + h;
    float aq = 0.f, ak = 0.f;
    #pragma unroll 8
    for (int c = 0; c < 64; c++) {
        aq += qb[(size_t)c * H_];
        ak += kb[(size_t)c * H_];
    }
    atomicAdd(&sq[b*3840 + h], aq * (1.0f/512.0f));
    atomicAdd(&sk[b*3840 + h], ak * (1.0f/512.0f));
}

// ---------------- Kernel 2: R -> gumbel -> sinkhorn -> perm ------------------
__global__ void perm_kernel(const float* __restrict__ sqg, const float* __restrict__ skg,
                            float* __restrict__ perm) {
    int b = blockIdx.x;
    int tid = threadIdx.x;
    __shared__ float sqs[NB*HB];
    __shared__ float sks[NB*HB];
    __shared__ float mat[NB][16];
    __shared__ float lse[NB];
    for (int i = tid; i < NB*HB; i += 256) {
        sqs[i] = sqg[b*3840 + i];
        sks[i] = skg[b*3840 + i];
    }
    __syncthreads();
    int i = tid / 15, j = tid % 15;
    if (tid < 225) {
        float acc = 0.f;
        for (int h = 0; h < HB; h++) acc += sqs[i*HB + h] * sks[j*HB + h];
        float R = acc * 0.044194173824159216f;
        float r0 = (R > 0.0f) ? logf(R) : NEG;
        int g = (b*15 + i)*15 + j;
        unsigned o0, o1;
        threefry2x32(0u, 42u, 0u, (unsigned)g, o0, o1);
        unsigned bits = o0 ^ o1;
        float u = __uint_as_float((bits >> 9) | 0x3f800000u) - 1.0f;
        float gum = -logf(-logf(u + 1e-6f) + 1e-6f);
        mat[i][j] = (r0 + gum) * INV_TEMP;
    }
    __syncthreads();
    for (int it = 0; it < 8; it++) {
        if (tid < 15) {
            float m = -3.4e38f;
            for (int jj = 0; jj < 15; jj++) m = fmaxf(m, mat[tid][jj]);
            float s = 0.f;
            for (int jj = 0; jj < 15; jj++) s += expf(mat[tid][jj] - m);
            lse[tid] = m + logf(s);
        }
        __syncthreads();
        if (tid < 225) mat[i][j] -= lse[i];
        __syncthreads();
        if (tid < 15) {
            float m = -3.4e38f;
            for (int ii = 0; ii < 15; ii++) m = fmaxf(m, mat[ii][tid]);
            float s = 0.f;
            for (int ii = 0; ii < 15; ii++) s += expf(mat[ii][tid] - m);
            lse[tid] = m + logf(s);
        }
        __syncthreads();
        if (tid < 225) mat[i][j] -= lse[j];
        __syncthreads();
    }
    if (tid < 225) perm[b*225 + tid] = expf(mat[i][j]);
}

// ---------------- Kernel 3a: K_cut fp16, tiled+padded [b][tile][key][528] ----
// grid 1024: (b 8, hch 8, chalf 2, ct 8) -- one 32-ch group per block.
__global__ __launch_bounds__(256)
void kcut_kernel(const float* __restrict__ k, const float* __restrict__ perm,
                 half_t* __restrict__ kc) {
    int bid  = blockIdx.x;
    int ct   = bid & 7;
    int chalf= (bid >> 3) & 1;
    int hch  = (bid >> 4) & 7;
    int b    = bid >> 7;
    int h0 = hch * 32;
    int tid = threadIdx.x;
    __shared__ float kt[32*481];     // [c' 32][n 15][h' 32], c-stride 481 (pad)
    __shared__ float pl[NB][CUT_];
    if (tid < NB*CUT_) pl[tid/CUT_][tid%CUT_] = perm[b*225 + (tid/CUT_)*15 + (tid%CUT_)];
    int cp = tid & 31;
    int hg = tid >> 5;               // 0..7 -> h' = hg*4+q
    int c0 = chalf*256 + ct*32;
    for (int it = 0; it < 15; it++) {
        int slot = tid + it*256;         // 0..3839
        int h4 = slot & 7;
        int n  = (slot >> 3) % 15;
        int cc = slot / 120;
        float4 vv = *(const float4*)&k[((size_t)(b*C_ + c0 + cc))*H_ + n*HB + h0 + h4*4];
        *(float4*)&kt[cc*481 + n*32 + h4*4] = vv;
    }
    __syncthreads();
    float acc[CUT_][4];
    #pragma unroll
    for (int j = 0; j < CUT_; j++) { acc[j][0]=0.f; acc[j][1]=0.f; acc[j][2]=0.f; acc[j][3]=0.f; }
    #pragma unroll
    for (int n = 0; n < NB; n++) {
        float kv0 = kt[cp*481 + n*32 + hg*4 + 0];
        float kv1 = kt[cp*481 + n*32 + hg*4 + 1];
        float kv2 = kt[cp*481 + n*32 + hg*4 + 2];
        float kv3 = kt[cp*481 + n*32 + hg*4 + 3];
        #pragma unroll
        for (int j = 0; j < CUT_; j++) {
            float p = pl[n][j];
            acc[j][0] += kv0*p; acc[j][1] += kv1*p; acc[j][2] += kv2*p; acc[j][3] += kv3*p;
        }
    }
    #pragma unroll
    for (int j = 0; j < CUT_; j++)
        for (int q2 = 0; q2 < 4; q2++) {
            int m = j*HB + h0 + hg*4 + q2;
            kc[(((size_t)b*64 + (m>>5))*32 + (m&31))*KROW + c0 + cp] = (half_t)acc[j][q2];
        }
}

// ---------------- Kernel 3b: V_cut fp16, tiled [b][tile][c][32] --------------
__global__ __launch_bounds__(256)
void vcut_kernel(const float* __restrict__ v, const float* __restrict__ perm,
                 half_t* __restrict__ vc) {
    int bc = blockIdx.x;             // b*512 + c
    int b = bc >> 9;
    int c = bc & 511;
    int h = threadIdx.x;
    __shared__ float pl[NB][CUT_];
    if (h < NB*CUT_) pl[h/CUT_][h%CUT_] = perm[b*225 + (h/CUT_)*15 + (h%CUT_)];
    __syncthreads();
    const float* vb = v + (size_t)bc * H_ + h;
    float av[CUT_] = {0,0,0,0,0,0,0,0};
    #pragma unroll
    for (int n = 0; n < NB; n++) {
        float vv = vb[n*HB];
        #pragma unroll
        for (int j = 0; j < CUT_; j++) av[j] += vv * pl[n][j];
    }
    #pragma unroll
    for (int j = 0; j < CUT_; j++)
        vc[(((size_t)b*64 + j*8 + (h>>5))*512 + c)*32 + (h&31)] = (half_t)av[j];
}

// ---------------- Kernel 4: flash attention, fp16 MFMA -----------------------
// grid 512: b = bid&7 (XCD affinity), htile = bid>>3; 64 q-rows/block.
// 8 waves (wm=w&3 row-group of 16, wc=w>>2 256-ch slice), 512 thr, 61.5KB LDS
// -> 2 blocks/CU = 16 waves/CU = 4 waves/SIMD (2x R2's latency hiding).
// K: single LDS buffer via global_load_lds; DMA issued after B1 (reads done),
//    drained by next B0's implicit vmcnt(0) -- stall covered by other waves.
// V: no LDS -- per-wave coalesced half8 register loads, direct PV B-operands.
// QK swapped (mfma(K,Q)): S rows lane-local -> local max + 2 shuffles.
// B1 is a raw asm barrier (lgkmcnt only -- no vmcnt drain).
__global__ __launch_bounds__(512, 4)
void attn_kernel(const float* __restrict__ q, const half_t* __restrict__ kc,
                 const half_t* __restrict__ vc, float* __restrict__ out,
                 float* __restrict__ stats) {
    __shared__ half_t ktile[32][KROW];     // 33792 B, single-buffered
    __shared__ float  spart[2][32][68];    // 17408 B, [wc][key][row] partial S
    __shared__ half_t pslab[2][64][40];    // 10240 B, [wc][row][key] P fp16
    __shared__ float  redbuf[8][2];

    int bid = blockIdx.x;
    int b   = bid & 7;
    int h0  = (bid >> 3) * 64;
    int tid = threadIdx.x;
    int w    = tid >> 6;
    int lane = tid & 63;
    int lm   = lane & 15;
    int quad = lane >> 4;
    int wm = w & 3;
    int wc = w >> 2;
    int row = 16*wm + lm;                  // this lane's softmax row (0..63)
    int key0 = 4*quad;

    const char* kbytes = (const char*)kc + (size_t)b * 64u * KT_BYTES;
    const char* vbytes = (const char*)vc + (size_t)b * 64u * VT_BYTES;

    // prologue: K(0) DMA overlaps Q staging (Q-loop barriers are lgkm-only,
    // so the DMA is not force-drained until the first B0)
    stage_tile8(kbytes, (char*)&ktile[0][0], w, lane, 33);

    // prologue-only overlay: qstage[64][68] f32 = 17408 B == spart exactly
    float (*qstage)[68] = reinterpret_cast<float(*)[68]>(&spart[0][0][0]);

    // ---- stage Q (fp32) and build hi/lo fp16 B-fragments, scaled by 1/T -----
    half8 qhi[8], qlo[8];
    for (int ch = 0; ch < 8; ch++) {
        int c0 = ch * 64;
        asm volatile("s_waitcnt lgkmcnt(0)\n\ts_barrier" ::: "memory");
        #pragma unroll
        for (int it = 0; it < 2; it++) {
            int slot = tid + it*512;        // 0..1023
            int cc = slot >> 4;             // 0..63
            int h4 = slot & 15;             // row quads (0..15 -> rows h4*4+j)
            float4 qv = *(const float4*)&q[((size_t)(b*C_ + c0 + cc))*H_ + h0 + h4*4];
            qstage[h4*4+0][cc] = qv.x;
            qstage[h4*4+1][cc] = qv.y;
            qstage[h4*4+2][cc] = qv.z;
            qstage[h4*4+3][cc] = qv.w;
        }
        asm volatile("s_waitcnt lgkmcnt(0)\n\ts_barrier" ::: "memory");
        if ((ch >> 2) == wc) {
            #pragma unroll
            for (int kk = 0; kk < 2; kk++) {
                int kb = (ch & 3)*2 + kk;
                const float* qp = &qstage[row][kk*32 + quad*8];
                float4 a = *(const float4*)qp;
                float4 c4 = *(const float4*)(qp + 4);
                float vals[8] = {a.x,a.y,a.z,a.w,c4.x,c4.y,c4.z,c4.w};
                half8 hh, hl;
                #pragma unroll
                for (int j = 0; j < 8; j++) {
                    float xv = vals[j] * INV_TEMP;
                    half_t h1 = (half_t)xv;
                    hh[j] = h1;
                    hl[j] = (half_t)(xv - (float)h1);
                }
                qhi[kb] = hh; qlo[kb] = hl;
            }
        }
    }

    floatx4 O[16];
    #pragma unroll
    for (int n = 0; n < 16; n++) O[n] = (floatx4)0.f;
    floatx4 Ol = (floatx4)0.f;             // row-sum column (denominator)
    float ms = -3.4e38f;                   // per-lane running max (row `row`)
    half8 vone;
    #pragma unroll
    for (int j = 0; j < 8; j++) vone[j] = (half_t)1.0f;

    for (int t = 0; t < 64; t++) {
        __syncthreads();   // B0: ktile=K(t) ready (vmcnt drained); spart free
        // V(t) register loads (consumed by PV at end of iter -- fully covered)
        half8 vreg[16];
        {
            const half_t* vt = (const half_t*)(vbytes + (size_t)t*VT_BYTES);
            #pragma unroll
            for (int n = 0; n < 16; n++)
                vreg[n] = *(const half8*)(vt + (256*wc + 16*n + lm)*32 + quad*8);
        }

        // ---- QK^T (swapped: A=K rows->keys, B=Q cols->q-rows), 256-ch slice
        floatx4 acc0 = (floatx4)0.f, acc1 = (floatx4)0.f;
        __builtin_amdgcn_s_setprio(1);
        #pragma unroll
        for (int kb = 0; kb < 8; kb++) {
            int coff = 256*wc + 32*kb + quad*8;
            half8 a0 = *(const half8*)&ktile[lm][coff];
            half8 a1 = *(const half8*)&ktile[16 + lm][coff];
            acc0 = __builtin_amdgcn_mfma_f32_16x16x32_f16(a0, qhi[kb], acc0, 0, 0, 0);
            acc0 = __builtin_amdgcn_mfma_f32_16x16x32_f16(a0, qlo[kb], acc0, 0, 0, 0);
            acc1 = __builtin_amdgcn_mfma_f32_16x16x32_f16(a1, qhi[kb], acc1, 0, 0, 0);
            acc1 = __builtin_amdgcn_mfma_f32_16x16x32_f16(a1, qlo[kb], acc1, 0, 0, 0);
        }
        __builtin_amdgcn_s_setprio(0);
        // lane holds S_part[key0+r][row] (acc0) and S_part[16+key0+r][row] (acc1)
        #pragma unroll
        for (int r = 0; r < 4; r++) {
            spart[wc][key0 + r][row]      = acc0[r];
            spart[wc][16 + key0 + r][row] = acc1[r];
        }
        // B1: raw barrier, LDS-drain only -- all ktile reads complete block-wide
        asm volatile("s_waitcnt lgkmcnt(0)\n\ts_barrier" ::: "memory");
        // K(t+1) DMA into the single buffer; drains at NEXT B0 (softmax+PV window)
        if (t + 1 < 64)
            stage_tile8(kbytes + (size_t)(t+1)*KT_BYTES, (char*)&ktile[0][0], w, lane, 33);

        // ---- add peer partial + online softmax (rows lane-local)
        float s0[4], s1[4];
        #pragma unroll
        for (int r = 0; r < 4; r++) {
            s0[r] = acc0[r] + spart[wc^1][key0 + r][row];
            s1[r] = acc1[r] + spart[wc^1][16 + key0 + r][row];
        }
        float m2 = fmaxf(fmaxf(fmaxf(s0[0],s0[1]), fmaxf(s0[2],s0[3])),
                         fmaxf(fmaxf(s1[0],s1[1]), fmaxf(s1[2],s1[3])));
        m2 = fmaxf(m2, __shfl_xor(m2, 16, 64));
        m2 = fmaxf(m2, __shfl_xor(m2, 32, 64));
        int need = (m2 > ms + 8.0f) ? 1 : 0;
        if (__any(need)) {
            float mn = fmaxf(ms, m2);
            float aown = __expf(ms - mn);
            ms = mn;
            float ar[4];
            #pragma unroll
            for (int r = 0; r < 4; r++) ar[r] = __shfl(aown, key0 + r, 64);
            #pragma unroll
            for (int r = 0; r < 4; r++) Ol[r] *= ar[r];
            #pragma unroll
            for (int n = 0; n < 16; n++) {
                #pragma unroll
                for (int r = 0; r < 4; r++) O[n][r] *= ar[r];
            }
        }
        #pragma unroll
        for (int r = 0; r < 4; r++) {
            pslab[wc][row][key0 + r]      = (half_t)__expf(s0[r] - ms);
            pslab[wc][row][16 + key0 + r] = (half_t)__expf(s1[r] - ms);
        }
        // per-wave self-roundtrip: wave reads only its own rows (no barrier)
        half8 pa = *(const half8*)&pslab[wc][row][quad*8];
        __builtin_amdgcn_s_setprio(1);
        #pragma unroll
        for (int n = 0; n < 16; n++)
            O[n] = __builtin_amdgcn_mfma_f32_16x16x32_f16(pa, vreg[n], O[n], 0, 0, 0);
        Ol = __builtin_amdgcn_mfma_f32_16x16x32_f16(pa, vone, Ol, 0, 0, 0);
        __builtin_amdgcn_s_setprio(0);
    }

    // ---- epilogue: normalize, store, instance-norm stats
    float inv4[4];
    #pragma unroll
    for (int r = 0; r < 4; r++) inv4[r] = 1.0f / Ol[r];
    float sa = 0.f, sb = 0.f;
    int rowg = h0 + 16*wm + quad*4;
    #pragma unroll
    for (int n = 0; n < 16; n++) {
        #pragma unroll
        for (int r = 0; r < 4; r++) {
            float o = O[n][r] * inv4[r];
            out[((size_t)b*H_ + rowg + r)*C_ + 256*wc + 16*n + lm] = o;
            sa += o; sb += o*o;
        }
    }
    #pragma unroll
    for (int msk = 1; msk < 64; msk <<= 1) {
        sa += __shfl_xor(sa, msk, 64);
        sb += __shfl_xor(sb, msk, 64);
    }
    if (lane == 0) { redbuf[w][0] = sa; redbuf[w][1] = sb; }
    __syncthreads();
    if (tid == 0) {
        float a = 0.f, c2 = 0.f;
        for (int w2 = 0; w2 < 8; w2++) { a += redbuf[w2][0]; c2 += redbuf[w2][1]; }
        atomicAdd(&stats[b*2    ], a);
        atomicAdd(&stats[b*2 + 1], c2);
    }
}

// ---------------- Kernel 5: instance norm (in place on d_out) ----------------
__global__ void norm_kernel(float* __restrict__ out, const float* __restrict__ stats) {
    size_t i = (size_t)blockIdx.x * 256 + threadIdx.x;
    int b = (int)(i >> 19);
    float4 vv = ((float4*)out)[i];
    const float inv = 1.0f / (4096.0f * 512.0f);
    float mu  = stats[b*2] * inv;
    float var = stats[b*2 + 1] * inv - mu*mu;
    float rs  = rsqrtf(var + 1e-5f);
    vv.x = (vv.x - mu) * rs;
    vv.y = (vv.y - mu) * rs;
    vv.z = (vv.z - mu) * rs;
    vv.w = (vv.w - mu) * rs;
    ((float4*)out)[i] = vv;
}

extern "C" void kernel_launch(void* const* d_in, const int* in_sizes, int n_in,
                              void* d_out, int out_size, void* d_ws, size_t ws_size,
                              hipStream_t stream) {
    const float* q = (const float*)d_in[0];
    const float* k = (const float*)d_in[1];
    const float* v = (const float*)d_in[2];
    float* out = (float*)d_out;
    if (ws_size < (size_t)WS_NEED) return;

    float*  sq    = (float*) ((char*)d_ws + SQ_OFFB);
    float*  sk    = (float*) ((char*)d_ws + SK_OFFB);
    float*  stats = (float*) ((char*)d_ws + ST_OFFB);
    float*  perm  = (float*) ((char*)d_ws + PERM_OFFB);
    half_t* kc    = (half_t*)((char*)d_ws + KC16_OFFB);
    half_t* vc    = (half_t*)((char*)d_ws + VC16_OFFB);

    hipMemsetAsync(d_ws, 0, (size_t)KC16_OFFB, stream);

    colmean_kernel<<<960,  256, 0, stream>>>(q, k, sq, sk);
    perm_kernel   <<<8,    256, 0, stream>>>(sq, sk, perm);
    kcut_kernel   <<<1024, 256, 0, stream>>>(k, perm, kc);
    vcut_kernel   <<<4096, 256, 0, stream>>>(v, perm, vc);
    attn_kernel   <<<512,  512, 0, stream>>>(q, kc, vc, out, stats);
    norm_kernel   <<<16384,256, 0, stream>>>(out, stats);
}

// Round 4
// 567.624 us; speedup vs baseline: 3.6488x; 3.6488x over previous
//
#include <hip/hip_runtime.h>
#include <stdint.h>

typedef _Float16 half_t;
typedef _Float16 half8 __attribute__((ext_vector_type(8)));
typedef float floatx4 __attribute__((ext_vector_type(4)));

#define B_ 8
#define C_ 512
#define H_ 4096
#define HB 256
#define NB 15
#define CUT_ 8
#define M_ 2048
#define INV_TEMP (1.0f/0.7f)
#define NEG (-1e9f)

// K tiles pre-padded to LDS layout: [32 keys][528 halves] (33 KB = 33 x 1KB DMA chunks)
// V tiles: [512 c][32 keys] contiguous (32 KB) -- reg-staged into padded LDS [512][40].
#define KROW 528
#define KT_BYTES 33792u
#define VT_BYTES 32768u

// Workspace layout (bytes) -- identical footprint to the proven 34.08 MB layout
#define SQ_OFFB   0u            // B*3840 floats
#define SK_OFFB   122880u
#define ST_OFFB   245760u       // B*2 floats
#define PERM_OFFB 245824u       // B*225 floats
#define KC16_OFFB 262144u       // [B][64][32][528] fp16 = 17.3 MB
#define VC16_OFFB (262144u + 17301504u)   // [B][64][512][32] fp16 = 16.8 MB
#define WS_NEED   (262144u + 17301504u + 16777216u)

// ---------------- threefry2x32 (JAX partitionable, key=(0,42)) ---------------
__device__ __forceinline__ unsigned rotl32(unsigned x, unsigned n) {
    return (x << n) | (x >> (32u - n));
}
__device__ __forceinline__ void threefry2x32(unsigned k0, unsigned k1,
                                             unsigned x0, unsigned x1,
                                             unsigned &o0, unsigned &o1) {
    unsigned k2 = 0x1BD11BDAu ^ k0 ^ k1;
    x0 += k0; x1 += k1;
    x0+=x1; x1=rotl32(x1,13); x1^=x0;
    x0+=x1; x1=rotl32(x1,15); x1^=x0;
    x0+=x1; x1=rotl32(x1,26); x1^=x0;
    x0+=x1; x1=rotl32(x1, 6); x1^=x0;
    x0+=k1; x1+=k2+1u;
    x0+=x1; x1=rotl32(x1,17); x1^=x0;
    x0+=x1; x1=rotl32(x1,29); x1^=x0;
    x0+=x1; x1=rotl32(x1,16); x1^=x0;
    x0+=x1; x1=rotl32(x1,24); x1^=x0;
    x0+=k2; x1+=k0+2u;
    x0+=x1; x1=rotl32(x1,13); x1^=x0;
    x0+=x1; x1=rotl32(x1,15); x1^=x0;
    x0+=x1; x1=rotl32(x1,26); x1^=x0;
    x0+=x1; x1=rotl32(x1, 6); x1^=x0;
    x0+=k0; x1+=k1+3u;
    x0+=x1; x1=rotl32(x1,17); x1^=x0;
    x0+=x1; x1=rotl32(x1,29); x1^=x0;
    x0+=x1; x1=rotl32(x1,16); x1^=x0;
    x0+=x1; x1=rotl32(x1,24); x1^=x0;
    x0+=k1; x1+=k2+4u;
    x0+=x1; x1=rotl32(x1,13); x1^=x0;
    x0+=x1; x1=rotl32(x1,15); x1^=x0;
    x0+=x1; x1=rotl32(x1,26); x1^=x0;
    x0+=x1; x1=rotl32(x1, 6); x1^=x0;
    x0+=k2; x1+=k0+5u;
    o0 = x0; o1 = x1;
}

// -------- async global->LDS DMA, 8-wave block (uniform LDS base + lane*16) ---
__device__ __forceinline__ void stage_tile8(const char* gsrc, char* lbase,
                                            int w, int lane, int nchunk) {
    #pragma unroll
    for (int i = 0; i < 5; i++) {
        int cc = w + 8*i;                 // wave-uniform chunk id
        if (cc < nchunk) {
            __builtin_amdgcn_global_load_lds(
                (const __attribute__((address_space(1))) void*)(uintptr_t)
                    (gsrc + (size_t)cc*1024u + (size_t)lane*16u),
                (__attribute__((address_space(3))) void*)(uintptr_t)
                    (lbase + (size_t)cc*1024u),
                16, 0, 0);
        }
    }
}

// ---------------- Kernel 1: per-(b,h) channel means of q,k -------------------
__global__ void colmean_kernel(const float* __restrict__ q, const float* __restrict__ k,
                               float* __restrict__ sq, float* __restrict__ sk) {
    int id  = blockIdx.x * 256 + threadIdx.x;
    int h   = id % 3840;
    int rest= id / 3840;
    int b   = rest % 8;
    int seg = rest / 8;
    int c0  = seg * 64;
    const float* qb = q + ((size_t)b*C_ + c0) * H_ + h;
    const float* kb = k + ((size_t)b*C_ + c0) * H_ + h;
    float aq = 0.f, ak = 0.f;
    #pragma unroll 8
    for (int c = 0; c < 64; c++) {
        aq += qb[(size_t)c * H_];
        ak += kb[(size_t)c * H_];
    }
    atomicAdd(&sq[b*3840 + h], aq * (1.0f/512.0f));
    atomicAdd(&sk[b*3840 + h], ak * (1.0f/512.0f));
}

// ---------------- Kernel 2: R -> gumbel -> sinkhorn -> perm ------------------
__global__ void perm_kernel(const float* __restrict__ sqg, const float* __restrict__ skg,
                            float* __restrict__ perm) {
    int b = blockIdx.x;
    int tid = threadIdx.x;
    __shared__ float sqs[NB*HB];
    __shared__ float sks[NB*HB];
    __shared__ float mat[NB][16];
    __shared__ float lse[NB];
    for (int i = tid; i < NB*HB; i += 256) {
        sqs[i] = sqg[b*3840 + i];
        sks[i] = skg[b*3840 + i];
    }
    __syncthreads();
    int i = tid / 15, j = tid % 15;
    if (tid < 225) {
        float acc = 0.f;
        for (int h = 0; h < HB; h++) acc += sqs[i*HB + h] * sks[j*HB + h];
        float R = acc * 0.044194173824159216f;
        float r0 = (R > 0.0f) ? logf(R) : NEG;
        int g = (b*15 + i)*15 + j;
        unsigned o0, o1;
        threefry2x32(0u, 42u, 0u, (unsigned)g, o0, o1);
        unsigned bits = o0 ^ o1;
        float u = __uint_as_float((bits >> 9) | 0x3f800000u) - 1.0f;
        float gum = -logf(-logf(u + 1e-6f) + 1e-6f);
        mat[i][j] = (r0 + gum) * INV_TEMP;
    }
    __syncthreads();
    for (int it = 0; it < 8; it++) {
        if (tid < 15) {
            float m = -3.4e38f;
            for (int jj = 0; jj < 15; jj++) m = fmaxf(m, mat[tid][jj]);
            float s = 0.f;
            for (int jj = 0; jj < 15; jj++) s += expf(mat[tid][jj] - m);
            lse[tid] = m + logf(s);
        }
        __syncthreads();
        if (tid < 225) mat[i][j] -= lse[i];
        __syncthreads();
        if (tid < 15) {
            float m = -3.4e38f;
            for (int ii = 0; ii < 15; ii++) m = fmaxf(m, mat[ii][tid]);
            float s = 0.f;
            for (int ii = 0; ii < 15; ii++) s += expf(mat[ii][tid] - m);
            lse[tid] = m + logf(s);
        }
        __syncthreads();
        if (tid < 225) mat[i][j] -= lse[j];
        __syncthreads();
    }
    if (tid < 225) perm[b*225 + tid] = expf(mat[i][j]);
}

// ---------------- Kernel 3a: K_cut fp16, tiled+padded [b][tile][key][528] ----
// grid 1024: (b 8, hch 8, chalf 2, ct 8) -- one 32-ch group per block.
__global__ __launch_bounds__(256)
void kcut_kernel(const float* __restrict__ k, const float* __restrict__ perm,
                 half_t* __restrict__ kc) {
    int bid  = blockIdx.x;
    int ct   = bid & 7;
    int chalf= (bid >> 3) & 1;
    int hch  = (bid >> 4) & 7;
    int b    = bid >> 7;
    int h0 = hch * 32;
    int tid = threadIdx.x;
    __shared__ float kt[32*481];     // [c' 32][n 15][h' 32], c-stride 481 (pad)
    __shared__ float pl[NB][CUT_];
    if (tid < NB*CUT_) pl[tid/CUT_][tid%CUT_] = perm[b*225 + (tid/CUT_)*15 + (tid%CUT_)];
    int cp = tid & 31;
    int hg = tid >> 5;               // 0..7 -> h' = hg*4+q
    int c0 = chalf*256 + ct*32;
    for (int it = 0; it < 15; it++) {
        int slot = tid + it*256;         // 0..3839
        int h4 = slot & 7;
        int n  = (slot >> 3) % 15;
        int cc = slot / 120;
        float4 vv = *(const float4*)&k[((size_t)(b*C_ + c0 + cc))*H_ + n*HB + h0 + h4*4];
        *(float4*)&kt[cc*481 + n*32 + h4*4] = vv;
    }
    __syncthreads();
    float acc[CUT_][4];
    #pragma unroll
    for (int j = 0; j < CUT_; j++) { acc[j][0]=0.f; acc[j][1]=0.f; acc[j][2]=0.f; acc[j][3]=0.f; }
    #pragma unroll
    for (int n = 0; n < NB; n++) {
        float kv0 = kt[cp*481 + n*32 + hg*4 + 0];
        float kv1 = kt[cp*481 + n*32 + hg*4 + 1];
        float kv2 = kt[cp*481 + n*32 + hg*4 + 2];
        float kv3 = kt[cp*481 + n*32 + hg*4 + 3];
        #pragma unroll
        for (int j = 0; j < CUT_; j++) {
            float p = pl[n][j];
            acc[j][0] += kv0*p; acc[j][1] += kv1*p; acc[j][2] += kv2*p; acc[j][3] += kv3*p;
        }
    }
    #pragma unroll
    for (int j = 0; j < CUT_; j++)
        for (int q2 = 0; q2 < 4; q2++) {
            int m = j*HB + h0 + hg*4 + q2;
            kc[(((size_t)b*64 + (m>>5))*32 + (m&31))*KROW + c0 + cp] = (half_t)acc[j][q2];
        }
}

// ---------------- Kernel 3b: V_cut fp16, tiled [b][tile][c][32] --------------
__global__ __launch_bounds__(256)
void vcut_kernel(const float* __restrict__ v, const float* __restrict__ perm,
                 half_t* __restrict__ vc) {
    int bc = blockIdx.x;             // b*512 + c
    int b = bc >> 9;
    int c = bc & 511;
    int h = threadIdx.x;
    __shared__ float pl[NB][CUT_];
    if (h < NB*CUT_) pl[h/CUT_][h%CUT_] = perm[b*225 + (h/CUT_)*15 + (h%CUT_)];
    __syncthreads();
    const float* vb = v + (size_t)bc * H_ + h;
    float av[CUT_] = {0,0,0,0,0,0,0,0};
    #pragma unroll
    for (int n = 0; n < NB; n++) {
        float vv = vb[n*HB];
        #pragma unroll
        for (int j = 0; j < CUT_; j++) av[j] += vv * pl[n][j];
    }
    #pragma unroll
    for (int j = 0; j < CUT_; j++)
        vc[(((size_t)b*64 + j*8 + (h>>5))*512 + c)*32 + (h&31)] = (half_t)av[j];
}

// ---------------- Kernel 4: flash attention, fp16 MFMA -----------------------
// grid 512: b = bid&7 (XCD affinity), htile = bid>>3; 64 q-rows/block.
// 8 waves (wm=w&3 row-group of 16, wc=w>>2 256-ch slice), 1 block/CU (136KB LDS).
// K: double-buffered LDS via global_load_lds DMA (issued at B0, full-iter window).
// V: staged ONCE per block into padded LDS [512][40] via regs (global bytes 1x,
//    bank-conflict-free PV reads) -- removes R2's 4x redundant V register loads,
//    cutting per-iter L2 traffic from ~97KB/32rows to 66KB/64rows.
// QK swapped (mfma(K,Q)): S rows lane-local; 2 barriers/iter (B1 lgkm-only).
__global__ __launch_bounds__(512, 2)
void attn_kernel(const float* __restrict__ q, const half_t* __restrict__ kc,
                 const half_t* __restrict__ vc, float* __restrict__ out,
                 float* __restrict__ stats) {
    __shared__ half_t ktile[2][32][KROW];  // 67584 B, double-buffered
    __shared__ half_t vtile[512][40];      // 40960 B, [c][key], pad 8 (2-way free)
    __shared__ float  spart[2][32][68];    // 17408 B, [wc][key][row] partial S
    __shared__ half_t pslab[2][64][40];    // 10240 B, [wc][row][key] P fp16
    __shared__ float  redbuf[8][2];

    int bid = blockIdx.x;
    int b   = bid & 7;
    int h0  = (bid >> 3) * 64;
    int tid = threadIdx.x;
    int w    = tid >> 6;
    int lane = tid & 63;
    int lm   = lane & 15;
    int quad = lane >> 4;
    int wm = w & 3;
    int wc = w >> 2;
    int row = 16*wm + lm;                  // this lane's softmax row (0..63)
    int key0 = 4*quad;

    const char* kbytes = (const char*)kc + (size_t)b * 64u * KT_BYTES;
    const char* vbytes = (const char*)vc + (size_t)b * 64u * VT_BYTES;

    // prologue: K(0) DMA overlaps Q staging (Q-loop barriers are lgkm-only,
    // so the DMA is not force-drained until the first B0)
    stage_tile8(kbytes, (char*)&ktile[0][0][0], w, lane, 33);

    // prologue-only overlay: qstage[64][68] f32 = 17408 B == spart exactly
    float (*qstage)[68] = reinterpret_cast<float(*)[68]>(&spart[0][0][0]);

    // ---- stage Q (fp32) and build hi/lo fp16 B-fragments, scaled by 1/T -----
    half8 qhi[8], qlo[8];
    for (int ch = 0; ch < 8; ch++) {
        int c0 = ch * 64;
        asm volatile("s_waitcnt lgkmcnt(0)\n\ts_barrier" ::: "memory");
        #pragma unroll
        for (int it = 0; it < 2; it++) {
            int slot = tid + it*512;        // 0..1023
            int cc = slot >> 4;             // 0..63
            int h4 = slot & 15;             // row quads (0..15 -> rows h4*4+j)
            float4 qv = *(const float4*)&q[((size_t)(b*C_ + c0 + cc))*H_ + h0 + h4*4];
            qstage[h4*4+0][cc] = qv.x;
            qstage[h4*4+1][cc] = qv.y;
            qstage[h4*4+2][cc] = qv.z;
            qstage[h4*4+3][cc] = qv.w;
        }
        asm volatile("s_waitcnt lgkmcnt(0)\n\ts_barrier" ::: "memory");
        if ((ch >> 2) == wc) {
            #pragma unroll
            for (int kk = 0; kk < 2; kk++) {
                int kb = (ch & 3)*2 + kk;
                const float* qp = &qstage[row][kk*32 + quad*8];
                float4 a = *(const float4*)qp;
                float4 c4 = *(const float4*)(qp + 4);
                float vals[8] = {a.x,a.y,a.z,a.w,c4.x,c4.y,c4.z,c4.w};
                half8 hh, hl;
                #pragma unroll
                for (int j = 0; j < 8; j++) {
                    float xv = vals[j] * INV_TEMP;
                    half_t h1 = (half_t)xv;
                    hh[j] = h1;
                    hl[j] = (half_t)(xv - (float)h1);
                }
                qhi[kb] = hh; qlo[kb] = hl;
            }
        }
    }

    floatx4 O[16];
    #pragma unroll
    for (int n = 0; n < 16; n++) O[n] = (floatx4)0.f;
    floatx4 Ol = (floatx4)0.f;             // row-sum column (denominator)
    float ms = -3.4e38f;                   // per-lane running max (row `row`)
    half8 vone;
    #pragma unroll
    for (int j = 0; j < 8; j++) vone[j] = (half_t)1.0f;

    int buf = 0;
    for (int t = 0; t < 64; t++) {
        __syncthreads();   // B0: ktile[buf]=K(t) ready (vmcnt drained); vtile free
        // V(t) global->reg (coalesced 64B/thread); LDS write after QK, pre-B1
        float4 vst[4];
        {
            const half_t* vt = (const half_t*)(vbytes + (size_t)t*VT_BYTES);
            #pragma unroll
            for (int i = 0; i < 4; i++) vst[i] = *(const float4*)(vt + tid*32 + i*8);
        }
        // K(t+1) DMA into idle buffer; drains at NEXT B0 (full-iter window)
        if (t + 1 < 64)
            stage_tile8(kbytes + (size_t)(t+1)*KT_BYTES, (char*)&ktile[buf^1][0][0], w, lane, 33);

        // ---- QK^T (swapped: A=K rows->keys, B=Q cols->q-rows), 256-ch slice
        floatx4 acc0 = (floatx4)0.f, acc1 = (floatx4)0.f;
        __builtin_amdgcn_s_setprio(1);
        #pragma unroll
        for (int kb = 0; kb < 8; kb++) {
            int coff = 256*wc + 32*kb + quad*8;
            half8 a0 = *(const half8*)&ktile[buf][lm][coff];
            half8 a1 = *(const half8*)&ktile[buf][16 + lm][coff];
            acc0 = __builtin_amdgcn_mfma_f32_16x16x32_f16(a0, qhi[kb], acc0, 0, 0, 0);
            acc0 = __builtin_amdgcn_mfma_f32_16x16x32_f16(a0, qlo[kb], acc0, 0, 0, 0);
            acc1 = __builtin_amdgcn_mfma_f32_16x16x32_f16(a1, qhi[kb], acc1, 0, 0, 0);
            acc1 = __builtin_amdgcn_mfma_f32_16x16x32_f16(a1, qlo[kb], acc1, 0, 0, 0);
        }
        __builtin_amdgcn_s_setprio(0);
        // write staged V into padded vtile (visible to all after B1's lgkm drain)
        #pragma unroll
        for (int i = 0; i < 4; i++) *(float4*)&vtile[tid][i*8] = vst[i];
        // lane holds S_part[key0+r][row] (acc0) and S_part[16+key0+r][row] (acc1)
        #pragma unroll
        for (int r = 0; r < 4; r++) {
            spart[wc][key0 + r][row]      = acc0[r];
            spart[wc][16 + key0 + r][row] = acc1[r];
        }
        // B1: raw barrier, LDS-drain only -- K(t+1) DMA stays in flight
        asm volatile("s_waitcnt lgkmcnt(0)\n\ts_barrier" ::: "memory");

        // ---- add peer partial + online softmax (rows lane-local)
        float s0[4], s1[4];
        #pragma unroll
        for (int r = 0; r < 4; r++) {
            s0[r] = acc0[r] + spart[wc^1][key0 + r][row];
            s1[r] = acc1[r] + spart[wc^1][16 + key0 + r][row];
        }
        float m2 = fmaxf(fmaxf(fmaxf(s0[0],s0[1]), fmaxf(s0[2],s0[3])),
                         fmaxf(fmaxf(s1[0],s1[1]), fmaxf(s1[2],s1[3])));
        m2 = fmaxf(m2, __shfl_xor(m2, 16, 64));
        m2 = fmaxf(m2, __shfl_xor(m2, 32, 64));
        int need = (m2 > ms + 8.0f) ? 1 : 0;
        if (__any(need)) {
            float mn = fmaxf(ms, m2);
            float aown = __expf(ms - mn);
            ms = mn;
            float ar[4];
            #pragma unroll
            for (int r = 0; r < 4; r++) ar[r] = __shfl(aown, key0 + r, 64);
            #pragma unroll
            for (int r = 0; r < 4; r++) Ol[r] *= ar[r];
            #pragma unroll
            for (int n = 0; n < 16; n++) {
                #pragma unroll
                for (int r = 0; r < 4; r++) O[n][r] *= ar[r];
            }
        }
        #pragma unroll
        for (int r = 0; r < 4; r++) {
            pslab[wc][row][key0 + r]      = (half_t)__expf(s0[r] - ms);
            pslab[wc][row][16 + key0 + r] = (half_t)__expf(s1[r] - ms);
        }
        // per-wave self-roundtrip: wave reads only its own rows (no barrier)
        half8 pa = *(const half8*)&pslab[wc][row][quad*8];
        __builtin_amdgcn_s_setprio(1);
        #pragma unroll
        for (int n = 0; n < 16; n++) {
            half8 vb = *(const half8*)&vtile[256*wc + 16*n + lm][quad*8];
            O[n] = __builtin_amdgcn_mfma_f32_16x16x32_f16(pa, vb, O[n], 0, 0, 0);
        }
        Ol = __builtin_amdgcn_mfma_f32_16x16x32_f16(pa, vone, Ol, 0, 0, 0);
        __builtin_amdgcn_s_setprio(0);
        buf ^= 1;
    }

    // ---- epilogue: normalize, store, instance-norm stats
    float inv4[4];
    #pragma unroll
    for (int r = 0; r < 4; r++) inv4[r] = 1.0f / Ol[r];
    float sa = 0.f, sb = 0.f;
    int rowg = h0 + 16*wm + quad*4;
    #pragma unroll
    for (int n = 0; n < 16; n++) {
        #pragma unroll
        for (int r = 0; r < 4; r++) {
            float o = O[n][r] * inv4[r];
            out[((size_t)b*H_ + rowg + r)*C_ + 256*wc + 16*n + lm] = o;
            sa += o; sb += o*o;
        }
    }
    #pragma unroll
    for (int msk = 1; msk < 64; msk <<= 1) {
        sa += __shfl_xor(sa, msk, 64);
        sb += __shfl_xor(sb, msk, 64);
    }
    if (lane == 0) { redbuf[w][0] = sa; redbuf[w][1] = sb; }
    __syncthreads();
    if (tid == 0) {
        float a = 0.f, c2 = 0.f;
        for (int w2 = 0; w2 < 8; w2++) { a += redbuf[w2][0]; c2 += redbuf[w2][1]; }
        atomicAdd(&stats[b*2    ], a);
        atomicAdd(&stats[b*2 + 1], c2);
    }
}

// ---------------- Kernel 5: instance norm (in place on d_out) ----------------
__global__ void norm_kernel(float* __restrict__ out, const float* __restrict__ stats) {
    size_t i = (size_t)blockIdx.x * 256 + threadIdx.x;
    int b = (int)(i >> 19);
    float4 vv = ((float4*)out)[i];
    const float inv = 1.0f / (4096.0f * 512.0f);
    float mu  = stats[b*2] * inv;
    float var = stats[b*2 + 1] * inv - mu*mu;
    float rs  = rsqrtf(var + 1e-5f);
    vv.x = (vv.x - mu) * rs;
    vv.y = (vv.y - mu) * rs;
    vv.z = (vv.z - mu) * rs;
    vv.w = (vv.w - mu) * rs;
    ((float4*)out)[i] = vv;
}

extern "C" void kernel_launch(void* const* d_in, const int* in_sizes, int n_in,
                              void* d_out, int out_size, void* d_ws, size_t ws_size,
                              hipStream_t stream) {
    const float* q = (const float*)d_in[0];
    const float* k = (const float*)d_in[1];
    const float* v = (const float*)d_in[2];
    float* out = (float*)d_out;
    if (ws_size < (size_t)WS_NEED) return;

    float*  sq    = (float*) ((char*)d_ws + SQ_OFFB);
    float*  sk    = (float*) ((char*)d_ws + SK_OFFB);
    float*  stats = (float*) ((char*)d_ws + ST_OFFB);
    float*  perm  = (float*) ((char*)d_ws + PERM_OFFB);
    half_t* kc    = (half_t*)((char*)d_ws + KC16_OFFB);
    half_t* vc    = (half_t*)((char*)d_ws + VC16_OFFB);

    hipMemsetAsync(d_ws, 0, (size_t)KC16_OFFB, stream);

    colmean_kernel<<<960,  256, 0, stream>>>(q, k, sq, sk);
    perm_kernel   <<<8,    256, 0, stream>>>(sq, sk, perm);
    kcut_kernel   <<<1024, 256, 0, stream>>>(k, perm, kc);
    vcut_kernel   <<<4096, 256, 0, stream>>>(v, perm, vc);
    attn_kernel   <<<512,  512, 0, stream>>>(q, kc, vc, out, stats);
    norm_kernel   <<<16384,256, 0, stream>>>(out, stats);
}